// Round 9
// baseline (187.211 us; speedup 1.0000x reference)
//
#include <hip/hip_runtime.h>
#include <hip/hip_bf16.h>
#include <math.h>

#define N_NODES 2048
#define F_DIM   128
#define H_HEADS 4
#define B_BATCH 8
#define LEAKY   0.2f

typedef float f32x4 __attribute__((ext_vector_type(4)));
typedef float f32x2 __attribute__((ext_vector_type(2)));
typedef short bf16x8 __attribute__((ext_vector_type(8)));   // 8 bf16 = 4 VGPRs
typedef float f32x4a __attribute__((ext_vector_type(4)));   // mfma acc

__device__ __forceinline__ float tanh_fast(float x) {
    const float e = __expf(2.0f * x);
    return 1.0f - 2.0f / (e + 1.0f);
}
__device__ __forceinline__ unsigned short f2bf(float x) {   // RTNE f32->bf16
    unsigned u = __float_as_uint(x);
    u += 0x7FFFu + ((u >> 16) & 1u);
    return (unsigned short)(u >> 16);
}
__device__ __forceinline__ float bf2f(unsigned short s) {
    return __uint_as_float(((unsigned)s) << 16);
}

// ---------------- Kernel 1: projections; packed [row][h] + planar [b][h][n] ----------------
__global__ __launch_bounds__(256) void gat_proj(const float* __restrict__ X,
                                                const float* __restrict__ wS,
                                                const float* __restrict__ wN,
                                                float* __restrict__ aSt,
                                                float* __restrict__ aNt,
                                                float* __restrict__ aNp) {
    const int wave = threadIdx.x >> 6;
    const int lane = threadIdx.x & 63;
    const int row  = blockIdx.x * 4 + wave;            // b*N + n
    const float* xr = X + (size_t)row * F_DIM;
    const float x0 = xr[lane];
    const float x1 = xr[lane + 64];
    float4 ps4, pn4;
    float* psv = (float*)&ps4;
    float* pnv = (float*)&pn4;
#pragma unroll
    for (int h = 0; h < H_HEADS; ++h) {
        float ps = x0 * wS[h * F_DIM + lane] + x1 * wS[h * F_DIM + 64 + lane];
        float pn = x0 * wN[h * F_DIM + lane] + x1 * wN[h * F_DIM + 64 + lane];
#pragma unroll
        for (int off = 32; off > 0; off >>= 1) {
            ps += __shfl_xor(ps, off);
            pn += __shfl_xor(pn, off);
        }
        psv[h] = ps;
        pnv[h] = pn;
    }
    if (lane == 0) {
        ((float4*)aSt)[row] = ps4;
        ((float4*)aNt)[row] = pn4;
        const int bb = row >> 11, nn = row & (N_NODES - 1);
#pragma unroll
        for (int h = 0; h < H_HEADS; ++h)
            aNp[((size_t)(bb * H_HEADS + h)) * N_NODES + nn] = pnv[h];
    }
}

// ---------------- Kernel 1b: per-(b,h) global max of a_neigh ----------------
__global__ __launch_bounds__(256) void gat_gmax(const float* __restrict__ aNt,
                                                float* __restrict__ gmax) {
    const int b = blockIdx.x;
    const int tid = threadIdx.x;
    const int lane = tid & 63;
    const int wv = tid >> 6;
    __shared__ float4 s_part[4];
    float4 m = make_float4(-1e30f, -1e30f, -1e30f, -1e30f);
    const float4* src = (const float4*)aNt + (size_t)b * N_NODES;
    for (int n = tid; n < N_NODES; n += 256) {
        const float4 v = src[n];
        m.x = fmaxf(m.x, v.x); m.y = fmaxf(m.y, v.y);
        m.z = fmaxf(m.z, v.z); m.w = fmaxf(m.w, v.w);
    }
#pragma unroll
    for (int off = 32; off > 0; off >>= 1) {
        m.x = fmaxf(m.x, __shfl_xor(m.x, off));
        m.y = fmaxf(m.y, __shfl_xor(m.y, off));
        m.z = fmaxf(m.z, __shfl_xor(m.z, off));
        m.w = fmaxf(m.w, __shfl_xor(m.w, off));
    }
    if (lane == 0) s_part[wv] = m;
    __syncthreads();
    if (tid == 0) {
        float4 r = s_part[0];
#pragma unroll
        for (int w = 1; w < 4; ++w) {
            r.x = fmaxf(r.x, s_part[w].x); r.y = fmaxf(r.y, s_part[w].y);
            r.z = fmaxf(r.z, s_part[w].z); r.w = fmaxf(r.w, s_part[w].w);
        }
        ((float4*)gmax)[b] = r;
    }
}

// ---------------- Kernel 1c: X -> X^T in split bf16 (hi + lo) ----------------
// XThi/XTlo layout: [b][f=128][k=2048] bf16.
__global__ __launch_bounds__(256) void gat_xtpose(const float* __restrict__ X,
                                                  unsigned short* __restrict__ XThi,
                                                  unsigned short* __restrict__ XTlo) {
    const int bb = blockIdx.x & 7;
    const int K0 = (blockIdx.x >> 3) << 7;              // 16 k-tiles of 128
    const int tid = threadIdx.x;
    __shared__ unsigned short ht[128][136];             // [f][k] +8 pad
    __shared__ unsigned short lt[128][136];
    const int f4 = (tid & 31) * 4;
    for (int kk = tid >> 5; kk < 128; kk += 8) {
        const float4 x = *(const float4*)&X[((size_t)(bb * N_NODES + K0 + kk)) * F_DIM + f4];
        const float xs[4] = {x.x, x.y, x.z, x.w};
#pragma unroll
        for (int q = 0; q < 4; ++q) {
            const unsigned short hi = f2bf(xs[q]);
            ht[f4 + q][kk] = hi;
            lt[f4 + q][kk] = f2bf(xs[q] - bf2f(hi));
        }
    }
    __syncthreads();
    const int f = tid >> 1, hf = tid & 1;
    const size_t obase = ((size_t)(bb * F_DIM + f)) * N_NODES + K0 + hf * 64;
#pragma unroll
    for (int c = 0; c < 64; c += 8) {
        *(bf16x8*)&XThi[obase + c] = *(const bf16x8*)&ht[f][hf * 64 + c];
        *(bf16x8*)&XTlo[obase + c] = *(const bf16x8*)&lt[f][hf * 64 + c];
    }
}

// ---------------- Kernel 2: dense masked-softmax + MFMA aggregation ----------------
// wg = (b, 32-row block); wave w = head w. K-loop over 2048 in steps of 32.
// P fragments computed in registers (exact mfma A-layout); X^T staged in LDS (dbuf).
__global__ __launch_bounds__(256, 2) void gat_dense(const float* __restrict__ A,
                                                    const float* __restrict__ aSt,
                                                    const float* __restrict__ aNp,
                                                    const float* __restrict__ gmax,
                                                    const unsigned short* __restrict__ XThi,
                                                    const unsigned short* __restrict__ XTlo,
                                                    float* __restrict__ out) {
    const int tid = threadIdx.x;
    const int bid = blockIdx.x;
    const int b = bid & 7;                              // batch-per-XCD
    const int Rbase = (bid >> 3) << 5;                  // 32-row block
    const int h = tid >> 6;                             // wave = head
    const int lane = tid & 63;
    const int mrow = lane & 15;                         // mfma M/N lane index
    const int kch = lane >> 4;                          // k-chunk 0..3 (8 k each)

    __shared__ unsigned short ldsXhi[2][128 * 40];      // [buf][f][40] (row 80 B, padded)
    __shared__ unsigned short ldsXlo[2][128 * 40];
    __shared__ float sml[128];                          // [h][32] row sums

    // per-row constants
    const int row0 = b * N_NODES + Rbase + mrow;
    const float g  = gmax[b * 4 + h];
    const float aS0 = aSt[(size_t)row0 * 4 + h];
    const float aS1 = aSt[(size_t)(row0 + 16) * 4 + h];
    float m0 = aS0 + g; m0 = fmaxf(m0, LEAKY * m0);
    float m1 = aS1 + g; m1 = fmaxf(m1, LEAKY * m1);

    const float* Ar0 = A + (size_t)row0 * N_NODES;
    const float* Ar1 = Ar0 + (size_t)16 * N_NODES;
    const float* aNh = aNp + ((size_t)(b * H_HEADS + h)) * N_NODES;

    // staging pointers: thread covers f = tid>>1, k-half = tid&1
    const int sf = tid >> 1, shf = tid & 1;
    const unsigned short* XThiB = XThi + ((size_t)(b * F_DIM + sf)) * N_NODES + shf * 16;
    const unsigned short* XTloB = XTlo + ((size_t)(b * F_DIM + sf)) * N_NODES + shf * 16;
    const int sdst = sf * 40 + shf * 16;

    f32x4a acc0[8], acc1[8];
#pragma unroll
    for (int ft = 0; ft < 8; ++ft) {
        acc0[ft] = (f32x4a){0.f, 0.f, 0.f, 0.f};
        acc1[ft] = (f32x4a){0.f, 0.f, 0.f, 0.f};
    }
    float ls0 = 0.f, ls1 = 0.f;

    // prologue: stage T=0 into buf 0
    bf16x8 rh0 = *(const bf16x8*)(XThiB);
    bf16x8 rh1 = *(const bf16x8*)(XThiB + 8);
    bf16x8 rl0 = *(const bf16x8*)(XTloB);
    bf16x8 rl1 = *(const bf16x8*)(XTloB + 8);
    *(bf16x8*)&ldsXhi[0][sdst] = rh0; *(bf16x8*)&ldsXhi[0][sdst + 8] = rh1;
    *(bf16x8*)&ldsXlo[0][sdst] = rl0; *(bf16x8*)&ldsXlo[0][sdst + 8] = rl1;
    __syncthreads();

    const int NS = N_NODES / 32;                        // 64 K-steps
    for (int s = 0; s < NS; ++s) {
        const int cur = s & 1;
        const int T = s << 5;
        // issue next stage loads early (hide HBM/L2 latency under this step)
        if (s + 1 < NS) {
            const int Tn = T + 32;
            rh0 = *(const bf16x8*)(XThiB + Tn);
            rh1 = *(const bf16x8*)(XThiB + Tn + 8);
            rl0 = *(const bf16x8*)(XTloB + Tn);
            rl1 = *(const bf16x8*)(XTloB + Tn + 8);
        }
        // P-generation: this lane's two A-fragments (rows mrow, mrow+16; k = T+kch*8..+8)
        const int ko = T + kch * 8;
        const f32x4 a0a = __builtin_nontemporal_load((const f32x4*)(Ar0 + ko));
        const f32x4 a0b = __builtin_nontemporal_load((const f32x4*)(Ar0 + ko + 4));
        const f32x4 a1a = __builtin_nontemporal_load((const f32x4*)(Ar1 + ko));
        const f32x4 a1b = __builtin_nontemporal_load((const f32x4*)(Ar1 + ko + 4));
        const f32x4 ana = *(const f32x4*)(aNh + ko);
        const f32x4 anb = *(const f32x4*)(aNh + ko + 4);
        const float a0v[8] = {a0a.x, a0a.y, a0a.z, a0a.w, a0b.x, a0b.y, a0b.z, a0b.w};
        const float a1v[8] = {a1a.x, a1a.y, a1a.z, a1a.w, a1b.x, a1b.y, a1b.z, a1b.w};
        const float anv[8] = {ana.x, ana.y, ana.z, ana.w, anb.x, anb.y, anb.z, anb.w};
        bf16x8 fr0, fr1;
#pragma unroll
        for (int j = 0; j < 8; ++j) {
            float v0 = aS0 + anv[j]; v0 = fmaxf(v0, LEAKY * v0);
            float v1 = aS1 + anv[j]; v1 = fmaxf(v1, LEAKY * v1);
            const float p0 = (a0v[j] != 0.f) ? __expf(v0 - m0) : 0.f;
            const float p1 = (a1v[j] != 0.f) ? __expf(v1 - m1) : 0.f;
            const unsigned short pb0 = f2bf(p0);
            const unsigned short pb1 = f2bf(p1);
            ls0 += bf2f(pb0);                           // sum the ROUNDED weights
            ls1 += bf2f(pb1);
            fr0[j] = (short)pb0;
            fr1[j] = (short)pb1;
        }
        // MFMA: hi pass then lo pass (dep distance 16)
#pragma unroll
        for (int ft = 0; ft < 8; ++ft) {
            const bf16x8 bh = *(const bf16x8*)&ldsXhi[cur][(ft * 16 + mrow) * 40 + kch * 8];
            acc0[ft] = __builtin_amdgcn_mfma_f32_16x16x32_bf16(fr0, bh, acc0[ft], 0, 0, 0);
            acc1[ft] = __builtin_amdgcn_mfma_f32_16x16x32_bf16(fr1, bh, acc1[ft], 0, 0, 0);
        }
#pragma unroll
        for (int ft = 0; ft < 8; ++ft) {
            const bf16x8 bl = *(const bf16x8*)&ldsXlo[cur][(ft * 16 + mrow) * 40 + kch * 8];
            acc0[ft] = __builtin_amdgcn_mfma_f32_16x16x32_bf16(fr0, bl, acc0[ft], 0, 0, 0);
            acc1[ft] = __builtin_amdgcn_mfma_f32_16x16x32_bf16(fr1, bl, acc1[ft], 0, 0, 0);
        }
        // write next stage, then one barrier per step
        if (s + 1 < NS) {
            const int nb = cur ^ 1;
            *(bf16x8*)&ldsXhi[nb][sdst] = rh0; *(bf16x8*)&ldsXhi[nb][sdst + 8] = rh1;
            *(bf16x8*)&ldsXlo[nb][sdst] = rl0; *(bf16x8*)&ldsXlo[nb][sdst + 8] = rl1;
        }
        __syncthreads();
    }

    // row sums: reduce over k-chunk lanes (same mrow at lane^16, lane^32)
    ls0 += __shfl_xor(ls0, 16); ls0 += __shfl_xor(ls0, 32);
    ls1 += __shfl_xor(ls1, 16); ls1 += __shfl_xor(ls1, 32);
    if (kch == 0) {
        sml[h * 32 + mrow] = ls0;
        sml[h * 32 + 16 + mrow] = ls1;
    }
    __syncthreads();

    // epilogue: D frag: col = lane&15 (feature), row = kch*4 + reg (graph row)
    const size_t outRow0 = (size_t)(b * N_NODES + Rbase);
#pragma unroll
    for (int i = 0; i < 4; ++i) {
        const int r0 = kch * 4 + i;
        const float inv0 = 1.0f / sml[h * 32 + r0];
        const float inv1 = 1.0f / sml[h * 32 + 16 + r0];
        float* o0 = out + (outRow0 + r0) * 512 + h * 128 + mrow;
        float* o1 = out + (outRow0 + 16 + r0) * 512 + h * 128 + mrow;
#pragma unroll
        for (int ft = 0; ft < 8; ++ft) {
            __builtin_nontemporal_store(tanh_fast(acc0[ft][i] * inv0), o0 + ft * 16);
            __builtin_nontemporal_store(tanh_fast(acc1[ft][i] * inv1), o1 + ft * 16);
        }
    }
}

// ---------------- Fallback (round-3 kernel, 98 us): sparse gather path ----------------
__global__ __launch_bounds__(256, 6) void gat_main_fb(const float* __restrict__ X,
                                                      const float* __restrict__ A,
                                                      const float* __restrict__ aSt,
                                                      const float* __restrict__ aNt,
                                                      const float* __restrict__ gmax,
                                                      float* __restrict__ out) {
    const int tid = threadIdx.x;
    const int bid = blockIdx.x;
    const int row = ((bid & 7) << 11) | (bid >> 3);
    const int b = row >> 11;
    const int lane = tid & 63;
    const int wv = tid >> 6;

    __shared__ short  s_idx[N_NODES];
    __shared__ float4 s_p4[256];
    __shared__ int    s_off[256];
    __shared__ float  s_red[4 * 512];
    __shared__ int    s_wtot[4];
    __shared__ float  s_M[4];
    __shared__ float  s_sv[4];
    __shared__ float  s_scr[16];

    const f32x4* Arow = (const f32x4*)(A + (size_t)row * N_NODES);
    const f32x4 a0 = __builtin_nontemporal_load(Arow + tid * 2);
    const f32x4 a1 = __builtin_nontemporal_load(Arow + tid * 2 + 1);

    if (tid < 4) {
        const float sv = aSt[(size_t)row * 4 + tid];
        const float g = gmax[b * 4 + tid];
        float v = sv + g;
        v = fmaxf(v, LEAKY * v);
        s_M[tid] = v;
        s_sv[tid] = sv;
    }

    const float av[8] = {a0.x, a0.y, a0.z, a0.w, a1.x, a1.y, a1.z, a1.w};
    int c = 0;
#pragma unroll
    for (int k = 0; k < 8; ++k) c += (av[k] != 0.0f) ? 1 : 0;

    int incl = c;
#pragma unroll
    for (int d = 1; d < 64; d <<= 1) {
        const int u = __shfl_up(incl, d);
        if (lane >= d) incl += u;
    }
    if (lane == 63) s_wtot[wv] = incl;
    __syncthreads();
    int wbase = 0;
#pragma unroll
    for (int w = 0; w < 4; ++w) wbase += (w < wv) ? s_wtot[w] : 0;
    const int cnt = s_wtot[0] + s_wtot[1] + s_wtot[2] + s_wtot[3];
    int pos = wbase + (incl - c);
#pragma unroll
    for (int k = 0; k < 8; ++k) {
        if (av[k] != 0.0f) s_idx[pos++] = (short)(tid * 8 + k);
    }
    __syncthreads();

    float acc[4][4];
#pragma unroll
    for (int h = 0; h < 4; ++h)
#pragma unroll
        for (int fi = 0; fi < 4; ++fi) acc[h][fi] = 0.0f;
    float lsum[4] = {0.0f, 0.0f, 0.0f, 0.0f};

    const int jsub = tid >> 5;
    const int f4 = tid & 31;
    const char* XbB = (const char*)(X + (size_t)b * N_NODES * F_DIM) + (f4 << 4);
    const float4* aNb4 = (const float4*)aNt + (size_t)b * N_NODES;

    for (int base = 0; base < cnt; base += 256) {
        const int clen = min(256, cnt - base);
        if (tid < clen) {
            const int m = s_idx[base + tid];
            const float4 t = aNb4[m];
            const float tv[4] = {t.x, t.y, t.z, t.w};
            float4 p4;
            float* pp = (float*)&p4;
#pragma unroll
            for (int h = 0; h < H_HEADS; ++h) {
                float v = s_sv[h] + tv[h];
                v = fmaxf(v, LEAKY * v);
                const float p = __expf(v - s_M[h]);
                pp[h] = p;
                lsum[h] += p;
            }
            s_p4[tid] = p4;
            s_off[tid] = m << 9;
        }
        __syncthreads();
#pragma unroll 4
        for (int j = jsub; j < clen; j += 8) {
            const float4 pv = s_p4[j];
            const float4 xv = *(const float4*)(XbB + (unsigned)s_off[j]);
#pragma unroll
            for (int h = 0; h < 4; ++h) {
                acc[h][0] = fmaf(((const float*)&pv)[h], xv.x, acc[h][0]);
                acc[h][1] = fmaf(((const float*)&pv)[h], xv.y, acc[h][1]);
                acc[h][2] = fmaf(((const float*)&pv)[h], xv.z, acc[h][2]);
                acc[h][3] = fmaf(((const float*)&pv)[h], xv.w, acc[h][3]);
            }
        }
        __syncthreads();
    }

#pragma unroll
    for (int h = 0; h < H_HEADS; ++h) {
        float v = lsum[h];
#pragma unroll
        for (int off = 32; off > 0; off >>= 1) v += __shfl_xor(v, off);
        if (lane == 0) s_scr[wv * 4 + h] = v;
    }
#pragma unroll
    for (int h = 0; h < 4; ++h)
#pragma unroll
        for (int fi = 0; fi < 4; ++fi)
            acc[h][fi] += __shfl_xor(acc[h][fi], 32);
    if (lane < 32) {
        float4* red4 = (float4*)s_red;
#pragma unroll
        for (int h = 0; h < 4; ++h)
            red4[wv * 128 + h * 32 + f4] =
                make_float4(acc[h][0], acc[h][1], acc[h][2], acc[h][3]);
    }
    __syncthreads();

    const int hf = tid * 2;
    const int h = tid >> 6;
    const float l = s_scr[h] + s_scr[4 + h] + s_scr[8 + h] + s_scr[12 + h];
    const float invl = 1.0f / l;
    float v0 = 0.0f, v1 = 0.0f;
#pragma unroll
    for (int w = 0; w < 4; ++w) {
        v0 += s_red[w * 512 + hf];
        v1 += s_red[w * 512 + hf + 1];
    }
    f32x2 o;
    o.x = tanh_fast(v0 * invl);
    o.y = tanh_fast(v1 * invl);
    __builtin_nontemporal_store(o, (f32x2*)&out[(size_t)row * 512 + hf]);
}

extern "C" void kernel_launch(void* const* d_in, const int* in_sizes, int n_in,
                              void* d_out, int out_size, void* d_ws, size_t ws_size,
                              hipStream_t stream) {
    const float* X  = (const float*)d_in[0];
    const float* A  = (const float*)d_in[1];
    const float* wS = (const float*)d_in[2];
    const float* wN = (const float*)d_in[3];
    float* out = (float*)d_out;

    const size_t nBNH = (size_t)B_BATCH * N_NODES * H_HEADS;    // 65536
    float* aSt = (float*)d_ws;
    float* aNt = aSt + nBNH;
    float* gmx = aNt + nBNH;
    float* aNp = gmx + B_BATCH * H_HEADS;
    unsigned short* XThi = (unsigned short*)(aNp + nBNH);
    unsigned short* XTlo = XThi + (size_t)B_BATCH * F_DIM * N_NODES;

    const size_t need = (nBNH * 3 + B_BATCH * H_HEADS) * 4
                        + (size_t)B_BATCH * F_DIM * N_NODES * 2 * 2;

    gat_proj<<<(B_BATCH * N_NODES) / 4, 256, 0, stream>>>(X, wS, wN, aSt, aNt, aNp);
    gat_gmax<<<B_BATCH, 256, 0, stream>>>(aNt, gmx);
    if (ws_size >= need) {
        gat_xtpose<<<B_BATCH * (N_NODES / 128), 256, 0, stream>>>(X, XThi, XTlo);
        gat_dense<<<B_BATCH * (N_NODES / 32), 256, 0, stream>>>(A, aSt, aNp, gmx,
                                                                XThi, XTlo, out);
    } else {
        gat_main_fb<<<B_BATCH * N_NODES, 256, 0, stream>>>(X, A, aSt, aNt, gmx, out);
    }
}

// Round 10
// 141.120 us; speedup vs baseline: 1.3266x; 1.3266x over previous
//
#include <hip/hip_runtime.h>
#include <hip/hip_bf16.h>
#include <math.h>

#define N_NODES 2048
#define F_DIM   128
#define H_HEADS 4
#define B_BATCH 8
#define LEAKY   0.2f

typedef float f32x4 __attribute__((ext_vector_type(4)));
typedef float f32x2 __attribute__((ext_vector_type(2)));
typedef short bf16x8 __attribute__((ext_vector_type(8)));   // 8 bf16 = 4 VGPRs
typedef float f32x4a __attribute__((ext_vector_type(4)));   // mfma acc

__device__ __forceinline__ float tanh_fast(float x) {
    const float e = __expf(2.0f * x);
    return 1.0f - 2.0f / (e + 1.0f);
}
__device__ __forceinline__ unsigned short f2bf(float x) {   // RTNE f32->bf16
    unsigned u = __float_as_uint(x);
    u += 0x7FFFu + ((u >> 16) & 1u);
    return (unsigned short)(u >> 16);
}
__device__ __forceinline__ float bf2f(unsigned short s) {
    return __uint_as_float(((unsigned)s) << 16);
}

// ---------------- Kernel 1: projections; packed [row][h] + planar [b][h][n] ----------------
__global__ __launch_bounds__(256) void gat_proj(const float* __restrict__ X,
                                                const float* __restrict__ wS,
                                                const float* __restrict__ wN,
                                                float* __restrict__ aSt,
                                                float* __restrict__ aNt,
                                                float* __restrict__ aNp) {
    const int wave = threadIdx.x >> 6;
    const int lane = threadIdx.x & 63;
    const int row  = blockIdx.x * 4 + wave;            // b*N + n
    const float* xr = X + (size_t)row * F_DIM;
    const float x0 = xr[lane];
    const float x1 = xr[lane + 64];
    float4 ps4, pn4;
    float* psv = (float*)&ps4;
    float* pnv = (float*)&pn4;
#pragma unroll
    for (int h = 0; h < H_HEADS; ++h) {
        float ps = x0 * wS[h * F_DIM + lane] + x1 * wS[h * F_DIM + 64 + lane];
        float pn = x0 * wN[h * F_DIM + lane] + x1 * wN[h * F_DIM + 64 + lane];
#pragma unroll
        for (int off = 32; off > 0; off >>= 1) {
            ps += __shfl_xor(ps, off);
            pn += __shfl_xor(pn, off);
        }
        psv[h] = ps;
        pnv[h] = pn;
    }
    if (lane == 0) {
        ((float4*)aSt)[row] = ps4;
        ((float4*)aNt)[row] = pn4;
        const int bb = row >> 11, nn = row & (N_NODES - 1);
#pragma unroll
        for (int h = 0; h < H_HEADS; ++h)
            aNp[((size_t)(bb * H_HEADS + h)) * N_NODES + nn] = pnv[h];
    }
}

// ---------------- Kernel 1b: per-(b,h) global max of a_neigh ----------------
__global__ __launch_bounds__(256) void gat_gmax(const float* __restrict__ aNt,
                                                float* __restrict__ gmax) {
    const int b = blockIdx.x;
    const int tid = threadIdx.x;
    const int lane = tid & 63;
    const int wv = tid >> 6;
    __shared__ float4 s_part[4];
    float4 m = make_float4(-1e30f, -1e30f, -1e30f, -1e30f);
    const float4* src = (const float4*)aNt + (size_t)b * N_NODES;
    for (int n = tid; n < N_NODES; n += 256) {
        const float4 v = src[n];
        m.x = fmaxf(m.x, v.x); m.y = fmaxf(m.y, v.y);
        m.z = fmaxf(m.z, v.z); m.w = fmaxf(m.w, v.w);
    }
#pragma unroll
    for (int off = 32; off > 0; off >>= 1) {
        m.x = fmaxf(m.x, __shfl_xor(m.x, off));
        m.y = fmaxf(m.y, __shfl_xor(m.y, off));
        m.z = fmaxf(m.z, __shfl_xor(m.z, off));
        m.w = fmaxf(m.w, __shfl_xor(m.w, off));
    }
    if (lane == 0) s_part[wv] = m;
    __syncthreads();
    if (tid == 0) {
        float4 r = s_part[0];
#pragma unroll
        for (int w = 1; w < 4; ++w) {
            r.x = fmaxf(r.x, s_part[w].x); r.y = fmaxf(r.y, s_part[w].y);
            r.z = fmaxf(r.z, s_part[w].z); r.w = fmaxf(r.w, s_part[w].w);
        }
        ((float4*)gmax)[b] = r;
    }
}

// ---------------- Kernel 1c: X -> fragment-ordered split-bf16 X^T ("XF") ----------------
// XF[b][s][pass][ft][kch][mrow][e]: element = X[b][k = s*32+kch*8+e][f = ft*16+mrow]
// per (b,s): 8192 shorts (pass0 = hi at 0, pass1 = lo at +4096).
__global__ __launch_bounds__(256) void gat_xf(const float* __restrict__ X,
                                              unsigned short* __restrict__ XF) {
    const int bid = blockIdx.x;
    const int b = bid & 7;                              // batch-per-XCD
    const int s = bid >> 3;                             // 0..63
    const int tid = threadIdx.x;
    const float* Xb = X + (size_t)b * N_NODES * F_DIM;
    unsigned short* dst = XF + (size_t)(b * 64 + s) * 8192;
#pragma unroll
    for (int r = 0; r < 2; ++r) {
        const int u = r * 256 + tid;                    // 0..511
        const int mrow = u & 15, kc = (u >> 4) & 3, ft = u >> 6;
        const int f = ft * 16 + mrow;
        const int k0 = s * 32 + kc * 8;
        bf16x8 hv, lv;
#pragma unroll
        for (int e = 0; e < 8; ++e) {
            const float x = Xb[(size_t)(k0 + e) * F_DIM + f];
            const unsigned short hi = f2bf(x);
            hv[e] = (short)hi;
            lv[e] = (short)f2bf(x - bf2f(hi));
        }
        const int off = ((ft * 4 + kc) << 7) + (mrow << 3);
        *(bf16x8*)&dst[off] = hv;
        *(bf16x8*)&dst[4096 + off] = lv;
    }
}

// ---------------- Kernel 2: dense masked-softmax + MFMA aggregation ----------------
// wg = (b, 32-row block); wave = head. Conflict-free fragment-ordered LDS staging,
// one-step register prefetch of XF tile + A/aNp rows.
__global__ __launch_bounds__(256, 2) void gat_dense(const float* __restrict__ A,
                                                    const float* __restrict__ aSt,
                                                    const float* __restrict__ aNp,
                                                    const float* __restrict__ gmax,
                                                    const unsigned short* __restrict__ XF,
                                                    float* __restrict__ out) {
    const int tid = threadIdx.x;
    const int bid = blockIdx.x;
    const int b = bid & 7;                              // batch-per-XCD
    const int Rbase = (bid >> 3) << 5;                  // 32-row block
    const int h = tid >> 6;                             // wave = head
    const int lane = tid & 63;
    const int mrow = lane & 15;                         // mfma lane index
    const int kch = lane >> 4;                          // k-chunk 0..3

    __shared__ short ldsX[2][8192];                     // 32 KB fragment-ordered tile
    __shared__ float sml[128];                          // [h][32] row sums

    // per-row constants
    const int row0 = b * N_NODES + Rbase + mrow;
    const float g  = gmax[b * 4 + h];
    const float aS0 = aSt[(size_t)row0 * 4 + h];
    const float aS1 = aSt[(size_t)(row0 + 16) * 4 + h];
    float m0 = aS0 + g; m0 = fmaxf(m0, LEAKY * m0);
    float m1 = aS1 + g; m1 = fmaxf(m1, LEAKY * m1);

    const float* Ar0 = A + (size_t)row0 * N_NODES;
    const float* Ar1 = Ar0 + (size_t)16 * N_NODES;
    const float* aNh = aNp + ((size_t)(b * H_HEADS + h)) * N_NODES;
    const unsigned short* XFb = XF + (size_t)(b * 64) * 8192 + tid * 8;

    f32x4a acc0[8], acc1[8];
#pragma unroll
    for (int ft = 0; ft < 8; ++ft) {
        acc0[ft] = (f32x4a){0.f, 0.f, 0.f, 0.f};
        acc1[ft] = (f32x4a){0.f, 0.f, 0.f, 0.f};
    }
    float ls0 = 0.f, ls1 = 0.f;

    // ---- prologue: XF regs + A regs for s=0; stage buf0 ----
    bf16x8 x0 = *(const bf16x8*)(XFb);
    bf16x8 x1 = *(const bf16x8*)(XFb + 2048);
    bf16x8 x2 = *(const bf16x8*)(XFb + 4096);
    bf16x8 x3 = *(const bf16x8*)(XFb + 6144);
    f32x4 a0a = __builtin_nontemporal_load((const f32x4*)(Ar0 + kch * 8));
    f32x4 a0b = __builtin_nontemporal_load((const f32x4*)(Ar0 + kch * 8 + 4));
    f32x4 a1a = __builtin_nontemporal_load((const f32x4*)(Ar1 + kch * 8));
    f32x4 a1b = __builtin_nontemporal_load((const f32x4*)(Ar1 + kch * 8 + 4));
    f32x4 ana = *(const f32x4*)(aNh + kch * 8);
    f32x4 anb = *(const f32x4*)(aNh + kch * 8 + 4);
    *(bf16x8*)&ldsX[0][tid * 8]        = x0;
    *(bf16x8*)&ldsX[0][tid * 8 + 2048] = x1;
    *(bf16x8*)&ldsX[0][tid * 8 + 4096] = x2;
    *(bf16x8*)&ldsX[0][tid * 8 + 6144] = x3;
    __syncthreads();

    const int NS = N_NODES / 32;                        // 64 K-steps
    for (int s = 0; s < NS; ++s) {
        const int cur = s & 1;
        const bool more = (s + 1) < NS;
        // issue next-step loads EARLY (consumed at bottom / next iter)
        bf16x8 nx0, nx1, nx2, nx3;
        f32x4 na0a, na0b, na1a, na1b, nana, nanb;
        if (more) {
            const unsigned short* src = XFb + (size_t)(s + 1) * 8192;
            nx0 = *(const bf16x8*)(src);
            nx1 = *(const bf16x8*)(src + 2048);
            nx2 = *(const bf16x8*)(src + 4096);
            nx3 = *(const bf16x8*)(src + 6144);
            const int ko = (s + 1) * 32 + kch * 8;
            na0a = __builtin_nontemporal_load((const f32x4*)(Ar0 + ko));
            na0b = __builtin_nontemporal_load((const f32x4*)(Ar0 + ko + 4));
            na1a = __builtin_nontemporal_load((const f32x4*)(Ar1 + ko));
            na1b = __builtin_nontemporal_load((const f32x4*)(Ar1 + ko + 4));
            nana = *(const f32x4*)(aNh + ko);
            nanb = *(const f32x4*)(aNh + ko + 4);
        }
        // ---- P-generation from CURRENT A regs (loaded one step ago) ----
        const float a0v[8] = {a0a.x, a0a.y, a0a.z, a0a.w, a0b.x, a0b.y, a0b.z, a0b.w};
        const float a1v[8] = {a1a.x, a1a.y, a1a.z, a1a.w, a1b.x, a1b.y, a1b.z, a1b.w};
        const float anv[8] = {ana.x, ana.y, ana.z, ana.w, anb.x, anb.y, anb.z, anb.w};
        unsigned q0[4], q1[4];
#pragma unroll
        for (int jj = 0; jj < 4; ++jj) {
            float ve = aS0 + anv[2 * jj];     ve = fmaxf(ve, LEAKY * ve);
            float vo = aS0 + anv[2 * jj + 1]; vo = fmaxf(vo, LEAKY * vo);
            const float pe0 = __expf(ve - m0) * a0v[2 * jj];
            const float po0 = __expf(vo - m0) * a0v[2 * jj + 1];
            float we = aS1 + anv[2 * jj];     we = fmaxf(we, LEAKY * we);
            float wo = aS1 + anv[2 * jj + 1]; wo = fmaxf(wo, LEAKY * wo);
            const float pe1 = __expf(we - m1) * a1v[2 * jj];
            const float po1 = __expf(wo - m1) * a1v[2 * jj + 1];
            asm("v_cvt_pk_bf16_f32 %0, %1, %2" : "=v"(q0[jj]) : "v"(pe0), "v"(po0));
            asm("v_cvt_pk_bf16_f32 %0, %1, %2" : "=v"(q1[jj]) : "v"(pe1), "v"(po1));
            // sum the ROUNDED weights (numerator/denominator errors cancel)
            ls0 += __uint_as_float(q0[jj] << 16) + __uint_as_float(q0[jj] & 0xffff0000u);
            ls1 += __uint_as_float(q1[jj] << 16) + __uint_as_float(q1[jj] & 0xffff0000u);
        }
        union { unsigned u[4]; bf16x8 v; } U0, U1;
        U0.u[0] = q0[0]; U0.u[1] = q0[1]; U0.u[2] = q0[2]; U0.u[3] = q0[3];
        U1.u[0] = q1[0]; U1.u[1] = q1[1]; U1.u[2] = q1[2]; U1.u[3] = q1[3];
        const bf16x8 fr0 = U0.v;
        const bf16x8 fr1 = U1.v;

        // ---- MFMA: conflict-free lane-linear B-fragment reads ----
#pragma unroll
        for (int ft = 0; ft < 8; ++ft) {
            const bf16x8 bh = *(const bf16x8*)&ldsX[cur][ft * 512 + lane * 8];
            acc0[ft] = __builtin_amdgcn_mfma_f32_16x16x32_bf16(fr0, bh, acc0[ft], 0, 0, 0);
            acc1[ft] = __builtin_amdgcn_mfma_f32_16x16x32_bf16(fr1, bh, acc1[ft], 0, 0, 0);
        }
#pragma unroll
        for (int ft = 0; ft < 8; ++ft) {
            const bf16x8 bl = *(const bf16x8*)&ldsX[cur][4096 + ft * 512 + lane * 8];
            acc0[ft] = __builtin_amdgcn_mfma_f32_16x16x32_bf16(fr0, bl, acc0[ft], 0, 0, 0);
            acc1[ft] = __builtin_amdgcn_mfma_f32_16x16x32_bf16(fr1, bl, acc1[ft], 0, 0, 0);
        }
        // ---- write next tile, rotate A regs, one barrier per step ----
        if (more) {
            const int nb = cur ^ 1;
            *(bf16x8*)&ldsX[nb][tid * 8]        = nx0;
            *(bf16x8*)&ldsX[nb][tid * 8 + 2048] = nx1;
            *(bf16x8*)&ldsX[nb][tid * 8 + 4096] = nx2;
            *(bf16x8*)&ldsX[nb][tid * 8 + 6144] = nx3;
            a0a = na0a; a0b = na0b; a1a = na1a; a1b = na1b;
            ana = nana; anb = nanb;
        }
        __syncthreads();
    }

    // ---- row sums: reduce over k-chunk lanes ----
    ls0 += __shfl_xor(ls0, 16); ls0 += __shfl_xor(ls0, 32);
    ls1 += __shfl_xor(ls1, 16); ls1 += __shfl_xor(ls1, 32);
    if (kch == 0) {
        sml[h * 32 + mrow] = ls0;
        sml[h * 32 + 16 + mrow] = ls1;
    }
    __syncthreads();

    // ---- epilogue: D frag col=lane&15 (feature), row=kch*4+i (graph row) ----
    const size_t outRow0 = (size_t)(b * N_NODES + Rbase);
#pragma unroll
    for (int i = 0; i < 4; ++i) {
        const int r0 = kch * 4 + i;
        const float inv0 = 1.0f / sml[h * 32 + r0];
        const float inv1 = 1.0f / sml[h * 32 + 16 + r0];
        float* o0 = out + (outRow0 + r0) * 512 + h * 128 + mrow;
        float* o1 = out + (outRow0 + 16 + r0) * 512 + h * 128 + mrow;
#pragma unroll
        for (int ft = 0; ft < 8; ++ft) {
            __builtin_nontemporal_store(tanh_fast(acc0[ft][i] * inv0), o0 + ft * 16);
            __builtin_nontemporal_store(tanh_fast(acc1[ft][i] * inv1), o1 + ft * 16);
        }
    }
}

// ---------------- Fallback (round-3 kernel, 98 us): sparse gather path ----------------
__global__ __launch_bounds__(256, 6) void gat_main_fb(const float* __restrict__ X,
                                                      const float* __restrict__ A,
                                                      const float* __restrict__ aSt,
                                                      const float* __restrict__ aNt,
                                                      const float* __restrict__ gmax,
                                                      float* __restrict__ out) {
    const int tid = threadIdx.x;
    const int bid = blockIdx.x;
    const int row = ((bid & 7) << 11) | (bid >> 3);
    const int b = row >> 11;
    const int lane = tid & 63;
    const int wv = tid >> 6;

    __shared__ short  s_idx[N_NODES];
    __shared__ float4 s_p4[256];
    __shared__ int    s_off[256];
    __shared__ float  s_red[4 * 512];
    __shared__ int    s_wtot[4];
    __shared__ float  s_M[4];
    __shared__ float  s_sv[4];
    __shared__ float  s_scr[16];

    const f32x4* Arow = (const f32x4*)(A + (size_t)row * N_NODES);
    const f32x4 a0 = __builtin_nontemporal_load(Arow + tid * 2);
    const f32x4 a1 = __builtin_nontemporal_load(Arow + tid * 2 + 1);

    if (tid < 4) {
        const float sv = aSt[(size_t)row * 4 + tid];
        const float g = gmax[b * 4 + tid];
        float v = sv + g;
        v = fmaxf(v, LEAKY * v);
        s_M[tid] = v;
        s_sv[tid] = sv;
    }

    const float av[8] = {a0.x, a0.y, a0.z, a0.w, a1.x, a1.y, a1.z, a1.w};
    int c = 0;
#pragma unroll
    for (int k = 0; k < 8; ++k) c += (av[k] != 0.0f) ? 1 : 0;

    int incl = c;
#pragma unroll
    for (int d = 1; d < 64; d <<= 1) {
        const int u = __shfl_up(incl, d);
        if (lane >= d) incl += u;
    }
    if (lane == 63) s_wtot[wv] = incl;
    __syncthreads();
    int wbase = 0;
#pragma unroll
    for (int w = 0; w < 4; ++w) wbase += (w < wv) ? s_wtot[w] : 0;
    const int cnt = s_wtot[0] + s_wtot[1] + s_wtot[2] + s_wtot[3];
    int pos = wbase + (incl - c);
#pragma unroll
    for (int k = 0; k < 8; ++k) {
        if (av[k] != 0.0f) s_idx[pos++] = (short)(tid * 8 + k);
    }
    __syncthreads();

    float acc[4][4];
#pragma unroll
    for (int h = 0; h < 4; ++h)
#pragma unroll
        for (int fi = 0; fi < 4; ++fi) acc[h][fi] = 0.0f;
    float lsum[4] = {0.0f, 0.0f, 0.0f, 0.0f};

    const int jsub = tid >> 5;
    const int f4 = tid & 31;
    const char* XbB = (const char*)(X + (size_t)b * N_NODES * F_DIM) + (f4 << 4);
    const float4* aNb4 = (const float4*)aNt + (size_t)b * N_NODES;

    for (int base = 0; base < cnt; base += 256) {
        const int clen = min(256, cnt - base);
        if (tid < clen) {
            const int m = s_idx[base + tid];
            const float4 t = aNb4[m];
            const float tv[4] = {t.x, t.y, t.z, t.w};
            float4 p4;
            float* pp = (float*)&p4;
#pragma unroll
            for (int h = 0; h < H_HEADS; ++h) {
                float v = s_sv[h] + tv[h];
                v = fmaxf(v, LEAKY * v);
                const float p = __expf(v - s_M[h]);
                pp[h] = p;
                lsum[h] += p;
            }
            s_p4[tid] = p4;
            s_off[tid] = m << 9;
        }
        __syncthreads();
#pragma unroll 4
        for (int j = jsub; j < clen; j += 8) {
            const float4 pv = s_p4[j];
            const float4 xv = *(const float4*)(XbB + (unsigned)s_off[j]);
            const float pr[4] = {pv.x, pv.y, pv.z, pv.w};
#pragma unroll
            for (int h = 0; h < 4; ++h) {
                acc[h][0] = fmaf(pr[h], xv.x, acc[h][0]);
                acc[h][1] = fmaf(pr[h], xv.y, acc[h][1]);
                acc[h][2] = fmaf(pr[h], xv.z, acc[h][2]);
                acc[h][3] = fmaf(pr[h], xv.w, acc[h][3]);
            }
        }
        __syncthreads();
    }

#pragma unroll
    for (int h = 0; h < H_HEADS; ++h) {
        float v = lsum[h];
#pragma unroll
        for (int off = 32; off > 0; off >>= 1) v += __shfl_xor(v, off);
        if (lane == 0) s_scr[wv * 4 + h] = v;
    }
#pragma unroll
    for (int h = 0; h < 4; ++h)
#pragma unroll
        for (int fi = 0; fi < 4; ++fi)
            acc[h][fi] += __shfl_xor(acc[h][fi], 32);
    if (lane < 32) {
        float4* red4 = (float4*)s_red;
#pragma unroll
        for (int h = 0; h < 4; ++h)
            red4[wv * 128 + h * 32 + f4] =
                make_float4(acc[h][0], acc[h][1], acc[h][2], acc[h][3]);
    }
    __syncthreads();

    const int hf = tid * 2;
    const int h = tid >> 6;
    const float l = s_scr[h] + s_scr[4 + h] + s_scr[8 + h] + s_scr[12 + h];
    const float invl = 1.0f / l;
    float v0 = 0.0f, v1 = 0.0f;
#pragma unroll
    for (int w = 0; w < 4; ++w) {
        v0 += s_red[w * 512 + hf];
        v1 += s_red[w * 512 + hf + 1];
    }
    f32x2 o;
    o.x = tanh_fast(v0 * invl);
    o.y = tanh_fast(v1 * invl);
    __builtin_nontemporal_store(o, (f32x2*)&out[(size_t)row * 512 + hf]);
}

extern "C" void kernel_launch(void* const* d_in, const int* in_sizes, int n_in,
                              void* d_out, int out_size, void* d_ws, size_t ws_size,
                              hipStream_t stream) {
    const float* X  = (const float*)d_in[0];
    const float* A  = (const float*)d_in[1];
    const float* wS = (const float*)d_in[2];
    const float* wN = (const float*)d_in[3];
    float* out = (float*)d_out;

    const size_t nBNH = (size_t)B_BATCH * N_NODES * H_HEADS;    // 65536
    float* aSt = (float*)d_ws;
    float* aNt = aSt + nBNH;
    float* gmx = aNt + nBNH;
    float* aNp = gmx + B_BATCH * H_HEADS;
    unsigned short* XF = (unsigned short*)(aNp + nBNH);

    const size_t need = (nBNH * 3 + B_BATCH * H_HEADS) * 4
                        + (size_t)B_BATCH * 64 * 8192 * 2;      // XF: 8 MB

    gat_proj<<<(B_BATCH * N_NODES) / 4, 256, 0, stream>>>(X, wS, wN, aSt, aNt, aNp);
    gat_gmax<<<B_BATCH, 256, 0, stream>>>(aNt, gmx);
    if (ws_size >= need) {
        gat_xf<<<B_BATCH * 64, 256, 0, stream>>>(X, XF);
        gat_dense<<<B_BATCH * (N_NODES / 32), 256, 0, stream>>>(A, aSt, aNp, gmx,
                                                                XF, out);
    } else {
        gat_main_fb<<<B_BATCH * N_NODES, 256, 0, stream>>>(X, A, aSt, aNt, gmx, out);
    }
}